// Round 1
// baseline (111.518 us; speedup 1.0000x reference)
//
#include <hip/hip_runtime.h>
#include <math.h>

#define NB     512
#define NV     6890
#define NF     13776
#define NVHD   20000
#define NPARTS 10
#define NTHREADS 512
#define NWAVES (NTHREADS/64)

__global__ __launch_bounds__(NTHREADS) void stab_kernel(
    const float* __restrict__ vertices,   // [B][V][3]
    const float* __restrict__ bary,       // [VHD][3]
    const int*   __restrict__ faces,      // [F][3]
    const int*   __restrict__ hd_fid,     // [VHD]
    const int*   __restrict__ part_fid,   // [F]
    float*       __restrict__ out)        // [B]
{
    __shared__ float4 sv[NV];                 // 110240 B, padded x,y,z,0
    __shared__ float  spart[NPARTS];
    __shared__ float  sredp[NWAVES][NPARTS];
    __shared__ float  sred8[NWAVES][8];

    const int tid  = threadIdx.x;
    const int b    = blockIdx.x;
    const int wave = tid >> 6;
    const int lane = tid & 63;
    const float* __restrict__ vb = vertices + (size_t)b * (NV * 3);

    // ---- Phase A: stage this batch's vertices into LDS (float4-padded) ----
    for (int v = tid; v < NV; v += NTHREADS) {
        float x = vb[3 * v + 0];
        float y = vb[3 * v + 1];
        float z = vb[3 * v + 2];
        sv[v] = make_float4(x, y, z, 0.f);
    }
    __syncthreads();

    // ---- Phase B: per-face signed volumes -> per-part sums ----
    float accp[NPARTS];
    #pragma unroll
    for (int q = 0; q < NPARTS; q++) accp[q] = 0.f;

    for (int f = tid; f < NF; f += NTHREADS) {
        int i0 = faces[3 * f + 0];
        int i1 = faces[3 * f + 1];
        int i2 = faces[3 * f + 2];
        int p  = part_fid[f];
        float4 t0 = sv[i0];
        float4 t1 = sv[i1];
        float4 t2 = sv[i2];
        float cx = t0.y * t1.z - t0.z * t1.y;
        float cy = t0.z * t1.x - t0.x * t1.z;
        float cz = t0.x * t1.y - t0.y * t1.x;
        float vol = (cx * t2.x + cy * t2.y + cz * t2.z) * (1.0f / 6.0f);
        #pragma unroll
        for (int q = 0; q < NPARTS; q++) accp[q] += (p == q) ? vol : 0.f;
    }
    // deterministic reduction: wave shuffle -> LDS -> 10 threads
    #pragma unroll
    for (int q = 0; q < NPARTS; q++) {
        float s = accp[q];
        #pragma unroll
        for (int off = 32; off > 0; off >>= 1) s += __shfl_down(s, off, 64);
        accp[q] = s;
    }
    if (lane == 0) {
        #pragma unroll
        for (int q = 0; q < NPARTS; q++) sredp[wave][q] = accp[q];
    }
    __syncthreads();
    if (tid < NPARTS) {
        float s = 0.f;
        #pragma unroll
        for (int w = 0; w < NWAVES; w++) s += sredp[w][tid];
        spart[tid] = s;
    }
    __syncthreads();

    // ---- Phase C: HD vertices, COM / CoP accumulators ----
    float sVx = 0.f, sVy = 0.f, sVz = 0.f, sVol = 0.f;
    float sPx = 0.f, sPy = 0.f, sPz = 0.f, sPw  = 0.f;

    #pragma unroll 2
    for (int v = tid; v < NVHD; v += NTHREADS) {
        int   fid = hd_fid[v];
        float b0 = bary[3 * v + 0];
        float b1 = bary[3 * v + 1];
        float b2 = bary[3 * v + 2];
        int i0 = faces[3 * fid + 0];
        int i1 = faces[3 * fid + 1];
        int i2 = faces[3 * fid + 2];
        int p  = part_fid[fid];
        float inv = 1.0f / (b0 + b1 + b2);
        float w0 = b0 * inv, w1 = b1 * inv, w2 = b2 * inv;
        float4 t0 = sv[i0];
        float4 t1 = sv[i1];
        float4 t2 = sv[i2];
        float x = w0 * t0.x + w1 * t1.x + w2 * t2.x;
        float y = w0 * t0.y + w1 * t1.y + w2 * t2.y;
        float z = w0 * t0.z + w1 * t1.z + w2 * t2.z;
        float vol = spart[p];
        float pw  = (y < 0.f) ? fmaf(-100.f, y, 1.f) : __expf(-10.f * y);
        sVx += x * vol;  sVy += y * vol;  sVz += z * vol;  sVol += vol;
        sPx += x * pw;   sPy += y * pw;   sPz += z * pw;   sPw  += pw;
    }

    float vals[8] = {sVx, sVy, sVz, sVol, sPx, sPy, sPz, sPw};
    #pragma unroll
    for (int q = 0; q < 8; q++) {
        float s = vals[q];
        #pragma unroll
        for (int off = 32; off > 0; off >>= 1) s += __shfl_down(s, off, 64);
        vals[q] = s;
    }
    if (lane == 0) {
        #pragma unroll
        for (int q = 0; q < 8; q++) sred8[wave][q] = vals[q];
    }
    __syncthreads();
    if (tid == 0) {
        float r[8];
        #pragma unroll
        for (int q = 0; q < 8; q++) {
            float s = 0.f;
            #pragma unroll
            for (int w = 0; w < NWAVES; w++) s += sred8[w][q];
            r[q] = s;
        }
        float invVol = 1.0f / r[3];
        float invPw  = 1.0f / (r[7] + 1e-6f);
        float comx = r[0] * invVol, comz = r[2] * invVol;
        float copx = r[4] * invPw,  copz = r[6] * invPw;
        float d0 = comx - copx, d2 = comz - copz;
        out[b] = sqrtf(d0 * d0 + d2 * d2);
    }
}

extern "C" void kernel_launch(void* const* d_in, const int* in_sizes, int n_in,
                              void* d_out, int out_size, void* d_ws, size_t ws_size,
                              hipStream_t stream) {
    const float* vertices = (const float*)d_in[0];
    const float* bary     = (const float*)d_in[1];
    const int*   faces    = (const int*)d_in[2];
    const int*   hd_fid   = (const int*)d_in[3];
    const int*   part_fid = (const int*)d_in[4];
    float* out = (float*)d_out;

    stab_kernel<<<NB, NTHREADS, 0, stream>>>(vertices, bary, faces, hd_fid, part_fid, out);
}

// Round 2
// 64.475 us; speedup vs baseline: 1.7296x; 1.7296x over previous
//
#include <hip/hip_runtime.h>
#include <math.h>

#define NB     512
#define NV     6890
#define NF     13776
#define NVHD   20000
#define NPARTS 10
#define NTHREADS 1024
#define NWAVES (NTHREADS/64)

// ---- Precompute batch-independent gather tables into workspace ----
__global__ void build_tables(const float* __restrict__ bary,
                             const int*   __restrict__ faces,
                             const int*   __restrict__ hd_fid,
                             const int*   __restrict__ part_fid,
                             int4*  __restrict__ f_table,   // [NF]  {i0,i1,i2,p}
                             int4*  __restrict__ hd_idx,    // [NVHD]{i0,i1,i2,p}
                             float4* __restrict__ hd_w)     // [NVHD]{w0,w1,w2,0}
{
    int i = blockIdx.x * blockDim.x + threadIdx.x;
    if (i < NF) {
        f_table[i] = make_int4(faces[3*i+0], faces[3*i+1], faces[3*i+2], part_fid[i]);
    }
    if (i < NVHD) {
        int fid = hd_fid[i];
        int i0 = faces[3*fid+0], i1 = faces[3*fid+1], i2 = faces[3*fid+2];
        int p  = part_fid[fid];
        hd_idx[i] = make_int4(i0, i1, i2, p);
        float b0 = bary[3*i+0], b1 = bary[3*i+1], b2 = bary[3*i+2];
        float inv = 1.0f / (b0 + b1 + b2);
        hd_w[i] = make_float4(b0*inv, b1*inv, b2*inv, 0.f);
    }
}

__global__ __launch_bounds__(NTHREADS) void stab_kernel(
    const float* __restrict__ vertices,   // [B][V][3]
    const int4*  __restrict__ f_table,    // [NF]
    const int4*  __restrict__ hd_idx,     // [NVHD]
    const float4* __restrict__ hd_w,      // [NVHD]
    float*       __restrict__ out)        // [B]
{
    __shared__ float4 sv[NV];                 // 110240 B
    __shared__ float  spart[NPARTS];
    __shared__ float  sredp[NWAVES][NPARTS];
    __shared__ float  sred8[NWAVES][8];

    const int tid  = threadIdx.x;
    const int b    = blockIdx.x;
    const int wave = tid >> 6;
    const int lane = tid & 63;
    const float* __restrict__ vb = vertices + (size_t)b * (NV * 3);

    // ---- Phase A: stage this batch's vertices into LDS ----
    for (int v = tid; v < NV; v += NTHREADS) {
        float x = vb[3 * v + 0];
        float y = vb[3 * v + 1];
        float z = vb[3 * v + 2];
        sv[v] = make_float4(x, y, z, 0.f);
    }
    __syncthreads();

    // ---- Phase B: per-face signed volumes -> per-part sums ----
    float accp[NPARTS];
    #pragma unroll
    for (int q = 0; q < NPARTS; q++) accp[q] = 0.f;

    #pragma unroll 2
    for (int f = tid; f < NF; f += NTHREADS) {
        int4 ft = f_table[f];
        float4 t0 = sv[ft.x];
        float4 t1 = sv[ft.y];
        float4 t2 = sv[ft.z];
        float cx = t0.y * t1.z - t0.z * t1.y;
        float cy = t0.z * t1.x - t0.x * t1.z;
        float cz = t0.x * t1.y - t0.y * t1.x;
        float vol = (cx * t2.x + cy * t2.y + cz * t2.z) * (1.0f / 6.0f);
        #pragma unroll
        for (int q = 0; q < NPARTS; q++) accp[q] += (ft.w == q) ? vol : 0.f;
    }
    #pragma unroll
    for (int q = 0; q < NPARTS; q++) {
        float s = accp[q];
        #pragma unroll
        for (int off = 32; off > 0; off >>= 1) s += __shfl_down(s, off, 64);
        accp[q] = s;
    }
    if (lane == 0) {
        #pragma unroll
        for (int q = 0; q < NPARTS; q++) sredp[wave][q] = accp[q];
    }
    __syncthreads();
    if (tid < NPARTS) {
        float s = 0.f;
        #pragma unroll
        for (int w = 0; w < NWAVES; w++) s += sredp[w][tid];
        spart[tid] = s;
    }
    __syncthreads();

    // ---- Phase C: HD vertices, COM / CoP accumulators ----
    float sVx = 0.f, sVy = 0.f, sVz = 0.f, sVol = 0.f;
    float sPx = 0.f, sPy = 0.f, sPz = 0.f, sPw  = 0.f;

    #pragma unroll 2
    for (int v = tid; v < NVHD; v += NTHREADS) {
        int4   hi = hd_idx[v];
        float4 hw = hd_w[v];
        float4 t0 = sv[hi.x];
        float4 t1 = sv[hi.y];
        float4 t2 = sv[hi.z];
        float x = hw.x * t0.x + hw.y * t1.x + hw.z * t2.x;
        float y = hw.x * t0.y + hw.y * t1.y + hw.z * t2.y;
        float z = hw.x * t0.z + hw.y * t1.z + hw.z * t2.z;
        float vol = spart[hi.w];
        float pw  = (y < 0.f) ? fmaf(-100.f, y, 1.f) : __expf(-10.f * y);
        sVx += x * vol;  sVy += y * vol;  sVz += z * vol;  sVol += vol;
        sPx += x * pw;   sPy += y * pw;   sPz += z * pw;   sPw  += pw;
    }

    float vals[8] = {sVx, sVy, sVz, sVol, sPx, sPy, sPz, sPw};
    #pragma unroll
    for (int q = 0; q < 8; q++) {
        float s = vals[q];
        #pragma unroll
        for (int off = 32; off > 0; off >>= 1) s += __shfl_down(s, off, 64);
        vals[q] = s;
    }
    if (lane == 0) {
        #pragma unroll
        for (int q = 0; q < 8; q++) sred8[wave][q] = vals[q];
    }
    __syncthreads();
    if (tid == 0) {
        float r[8];
        #pragma unroll
        for (int q = 0; q < 8; q++) {
            float s = 0.f;
            #pragma unroll
            for (int w = 0; w < NWAVES; w++) s += sred8[w][q];
            r[q] = s;
        }
        float invVol = 1.0f / r[3];
        float invPw  = 1.0f / (r[7] + 1e-6f);
        float comx = r[0] * invVol, comz = r[2] * invVol;
        float copx = r[4] * invPw,  copz = r[6] * invPw;
        float d0 = comx - copx, d2 = comz - copz;
        out[b] = sqrtf(d0 * d0 + d2 * d2);
    }
}

extern "C" void kernel_launch(void* const* d_in, const int* in_sizes, int n_in,
                              void* d_out, int out_size, void* d_ws, size_t ws_size,
                              hipStream_t stream) {
    const float* vertices = (const float*)d_in[0];
    const float* bary     = (const float*)d_in[1];
    const int*   faces    = (const int*)d_in[2];
    const int*   hd_fid   = (const int*)d_in[3];
    const int*   part_fid = (const int*)d_in[4];
    float* out = (float*)d_out;

    // workspace layout
    char* ws = (char*)d_ws;
    int4*   f_table = (int4*)ws;                                  // NF * 16
    int4*   hd_idx  = (int4*)(ws + (size_t)NF * 16);              // NVHD * 16
    float4* hd_w    = (float4*)(ws + (size_t)NF * 16 + (size_t)NVHD * 16);

    build_tables<<<(NVHD + 255) / 256, 256, 0, stream>>>(bary, faces, hd_fid, part_fid,
                                                         f_table, hd_idx, hd_w);
    stab_kernel<<<NB, NTHREADS, 0, stream>>>(vertices, f_table, hd_idx, hd_w, out);
}

// Round 3
// 60.119 us; speedup vs baseline: 1.8550x; 1.0725x over previous
//
#include <hip/hip_runtime.h>
#include <math.h>

#define NB     512
#define NV     6890
#define NF     13776
#define NVHD   20000
#define NPARTS 10
#define NTHREADS 1024
#define NWAVES (NTHREADS/64)

// ---- Precompute batch-independent gather tables into workspace ----
__global__ void build_tables(const float* __restrict__ bary,
                             const int*   __restrict__ faces,
                             const int*   __restrict__ hd_fid,
                             const int*   __restrict__ part_fid,
                             int4*  __restrict__ f_table,   // [NF]  {i0,i1,i2,p}
                             int4*  __restrict__ hd_idx,    // [NVHD]{i0,i1,i2,p}
                             float4* __restrict__ hd_w)     // [NVHD]{w0,w1,w2,0}
{
    int i = blockIdx.x * blockDim.x + threadIdx.x;
    if (i < NF) {
        f_table[i] = make_int4(faces[3*i+0], faces[3*i+1], faces[3*i+2], part_fid[i]);
    }
    if (i < NVHD) {
        int fid = hd_fid[i];
        int i0 = faces[3*fid+0], i1 = faces[3*fid+1], i2 = faces[3*fid+2];
        int p  = part_fid[fid];
        hd_idx[i] = make_int4(i0, i1, i2, p);
        float b0 = bary[3*i+0], b1 = bary[3*i+1], b2 = bary[3*i+2];
        float inv = 1.0f / (b0 + b1 + b2);
        hd_w[i] = make_float4(b0*inv, b1*inv, b2*inv, 0.f);
    }
}

__global__ __launch_bounds__(NTHREADS) void stab_kernel(
    const float* __restrict__ vertices,   // [B][V][3]
    const int4*  __restrict__ f_table,    // [NF]
    const int4*  __restrict__ hd_idx,     // [NVHD]
    const float4* __restrict__ hd_w,      // [NVHD]
    float*       __restrict__ out)        // [B]
{
    __shared__ float sx[NV];              // SoA: random b32 gathers, 2-way conflicts free
    __shared__ float sy[NV];
    __shared__ float sz[NV];
    __shared__ float spart[NPARTS];
    __shared__ float sredp[NWAVES][NPARTS];
    __shared__ float sred8[NWAVES][8];

    const int tid  = threadIdx.x;
    const int b    = blockIdx.x;
    const int wave = tid >> 6;
    const int lane = tid & 63;
    const float* __restrict__ vb = vertices + (size_t)b * (NV * 3);

    // ---- Phase A: stage this batch's vertices into LDS (SoA) ----
    for (int v = tid; v < NV; v += NTHREADS) {
        sx[v] = vb[3 * v + 0];
        sy[v] = vb[3 * v + 1];
        sz[v] = vb[3 * v + 2];
    }
    __syncthreads();

    // ---- Phase B: per-face signed volumes -> per-part sums ----
    float accp[NPARTS];
    #pragma unroll
    for (int q = 0; q < NPARTS; q++) accp[q] = 0.f;

    #pragma unroll 2
    for (int f = tid; f < NF; f += NTHREADS) {
        int4 ft = f_table[f];
        float x0 = sx[ft.x], y0 = sy[ft.x], z0 = sz[ft.x];
        float x1 = sx[ft.y], y1 = sy[ft.y], z1 = sz[ft.y];
        float x2 = sx[ft.z], y2 = sy[ft.z], z2 = sz[ft.z];
        float cx = y0 * z1 - z0 * y1;
        float cy = z0 * x1 - x0 * z1;
        float cz = x0 * y1 - y0 * x1;
        float vol = (cx * x2 + cy * y2 + cz * z2) * (1.0f / 6.0f);
        #pragma unroll
        for (int q = 0; q < NPARTS; q++) accp[q] += (ft.w == q) ? vol : 0.f;
    }
    #pragma unroll
    for (int q = 0; q < NPARTS; q++) {
        float s = accp[q];
        #pragma unroll
        for (int off = 32; off > 0; off >>= 1) s += __shfl_down(s, off, 64);
        accp[q] = s;
    }
    if (lane == 0) {
        #pragma unroll
        for (int q = 0; q < NPARTS; q++) sredp[wave][q] = accp[q];
    }
    __syncthreads();
    if (tid < NPARTS) {
        float s = 0.f;
        #pragma unroll
        for (int w = 0; w < NWAVES; w++) s += sredp[w][tid];
        spart[tid] = s;
    }
    __syncthreads();

    // ---- Phase C: HD vertices, COM / CoP accumulators ----
    float sVx = 0.f, sVy = 0.f, sVz = 0.f, sVol = 0.f;
    float sPx = 0.f, sPy = 0.f, sPz = 0.f, sPw  = 0.f;

    #pragma unroll 4
    for (int v = tid; v < NVHD; v += NTHREADS) {
        int4   hi = hd_idx[v];
        float4 hw = hd_w[v];
        float x0 = sx[hi.x], y0 = sy[hi.x], z0 = sz[hi.x];
        float x1 = sx[hi.y], y1 = sy[hi.y], z1 = sz[hi.y];
        float x2 = sx[hi.z], y2 = sy[hi.z], z2 = sz[hi.z];
        float x = hw.x * x0 + hw.y * x1 + hw.z * x2;
        float y = hw.x * y0 + hw.y * y1 + hw.z * y2;
        float z = hw.x * z0 + hw.y * z1 + hw.z * z2;
        float vol = spart[hi.w];
        float pw  = (y < 0.f) ? fmaf(-100.f, y, 1.f) : __expf(-10.f * y);
        sVx += x * vol;  sVy += y * vol;  sVz += z * vol;  sVol += vol;
        sPx += x * pw;   sPy += y * pw;   sPz += z * pw;   sPw  += pw;
    }

    float vals[8] = {sVx, sVy, sVz, sVol, sPx, sPy, sPz, sPw};
    #pragma unroll
    for (int q = 0; q < 8; q++) {
        float s = vals[q];
        #pragma unroll
        for (int off = 32; off > 0; off >>= 1) s += __shfl_down(s, off, 64);
        vals[q] = s;
    }
    if (lane == 0) {
        #pragma unroll
        for (int q = 0; q < 8; q++) sred8[wave][q] = vals[q];
    }
    __syncthreads();
    if (tid == 0) {
        float r[8];
        #pragma unroll
        for (int q = 0; q < 8; q++) {
            float s = 0.f;
            #pragma unroll
            for (int w = 0; w < NWAVES; w++) s += sred8[w][q];
            r[q] = s;
        }
        float invVol = 1.0f / r[3];
        float invPw  = 1.0f / (r[7] + 1e-6f);
        float comx = r[0] * invVol, comz = r[2] * invVol;
        float copx = r[4] * invPw,  copz = r[6] * invPw;
        float d0 = comx - copx, d2 = comz - copz;
        out[b] = sqrtf(d0 * d0 + d2 * d2);
    }
}

extern "C" void kernel_launch(void* const* d_in, const int* in_sizes, int n_in,
                              void* d_out, int out_size, void* d_ws, size_t ws_size,
                              hipStream_t stream) {
    const float* vertices = (const float*)d_in[0];
    const float* bary     = (const float*)d_in[1];
    const int*   faces    = (const int*)d_in[2];
    const int*   hd_fid   = (const int*)d_in[3];
    const int*   part_fid = (const int*)d_in[4];
    float* out = (float*)d_out;

    // workspace layout
    char* ws = (char*)d_ws;
    int4*   f_table = (int4*)ws;                                  // NF * 16
    int4*   hd_idx  = (int4*)(ws + (size_t)NF * 16);              // NVHD * 16
    float4* hd_w    = (float4*)(ws + (size_t)NF * 16 + (size_t)NVHD * 16);

    build_tables<<<(NVHD + 255) / 256, 256, 0, stream>>>(bary, faces, hd_fid, part_fid,
                                                         f_table, hd_idx, hd_w);
    stab_kernel<<<NB, NTHREADS, 0, stream>>>(vertices, f_table, hd_idx, hd_w, out);
}

// Round 5
// 59.035 us; speedup vs baseline: 1.8890x; 1.0184x over previous
//
#include <hip/hip_runtime.h>
#include <math.h>

#define NB     512
#define NV     6890
#define NF     13776
#define NVHD   20000
#define NPARTS 10
#define NTHREADS 1024
#define NWAVES (NTHREADS/64)
#define CUT    6698   // verts >= CUT (192 of them) are read from global (L2-hot)

// ---- Precompute batch-independent packed gather tables (lossless indices) ----
__global__ void build_tables(const float* __restrict__ bary,
                             const int*   __restrict__ faces,
                             const int*   __restrict__ hd_fid,
                             const int*   __restrict__ part_fid,
                             uint2* __restrict__ f_pack,    // [NF]  {i0|i1<<16, i2|p<<16}
                             uint4* __restrict__ hd_pack)   // [NVHD]{i0|i1<<16, i2|p<<16, w0, w1}
{
    int i = blockIdx.x * blockDim.x + threadIdx.x;
    if (i < NF) {
        unsigned a = (unsigned)faces[3*i+0] | ((unsigned)faces[3*i+1] << 16);
        unsigned b = (unsigned)faces[3*i+2] | ((unsigned)part_fid[i]  << 16);
        f_pack[i] = make_uint2(a, b);
    }
    if (i < NVHD) {
        int fid = hd_fid[i];
        unsigned a = (unsigned)faces[3*fid+0] | ((unsigned)faces[3*fid+1] << 16);
        unsigned b = (unsigned)faces[3*fid+2] | ((unsigned)part_fid[fid]  << 16);
        float b0 = bary[3*i+0], b1 = bary[3*i+1], b2 = bary[3*i+2];
        float inv = 1.0f / (b0 + b1 + b2);
        hd_pack[i] = make_uint4(a, b, __float_as_uint(b0*inv), __float_as_uint(b1*inv));
    }
}

__global__ __launch_bounds__(NTHREADS, 8) void stab_kernel(
    const float* __restrict__ vertices,   // [B][V][3] f32
    const uint2* __restrict__ f_pack,     // [NF]
    const uint4* __restrict__ hd_pack,    // [NVHD]
    float*       __restrict__ out)        // [B]
{
    // 53584 + 26792 + 40 + 640 = 81056 B -> fits 2 blocks/CU (<= 81920 each)
    __shared__ float2 sxy[CUT];
    __shared__ float  szz[CUT];
    __shared__ float  spart[NPARTS];
    __shared__ float  sredp[NWAVES][NPARTS];   // Phase-B partials; reused after Phase C

    const int tid  = threadIdx.x;
    const int b    = blockIdx.x;
    const int wave = tid >> 6;
    const int lane = tid & 63;
    const float* __restrict__ vb = vertices + (size_t)b * (NV * 3);

    // ---- Phase A: stage first CUT vertices into LDS (f32, xy packed) ----
    for (int v = tid; v < CUT; v += NTHREADS) {
        float x = vb[3 * v + 0];
        float y = vb[3 * v + 1];
        float z = vb[3 * v + 2];
        sxy[v] = make_float2(x, y);
        szz[v] = z;
    }
    __syncthreads();

    // gather helper: LDS for idx<CUT, global fallback for the 192-vertex tail
#define GETV(idx, X, Y, Z) do {                                   \
        int _ic = (idx) < CUT ? (idx) : CUT - 1;                  \
        float2 _t = sxy[_ic]; float _z = szz[_ic];                \
        X = _t.x; Y = _t.y; Z = _z;                               \
        if ((idx) >= CUT) {                                       \
            X = vb[3*(idx)+0]; Y = vb[3*(idx)+1]; Z = vb[3*(idx)+2]; \
        }                                                         \
    } while (0)

    // ---- Phase B: per-face signed volumes -> per-part sums ----
    float accp[NPARTS];
    #pragma unroll
    for (int q = 0; q < NPARTS; q++) accp[q] = 0.f;

    #pragma unroll 2
    for (int f = tid; f < NF; f += NTHREADS) {
        uint2 ft = f_pack[f];
        int i0 = ft.x & 0xFFFF, i1 = ft.x >> 16;
        int i2 = ft.y & 0xFFFF, p  = ft.y >> 16;
        float x0, y0, z0, x1, y1, z1, x2, y2, z2;
        GETV(i0, x0, y0, z0);
        GETV(i1, x1, y1, z1);
        GETV(i2, x2, y2, z2);
        float cx = y0 * z1 - z0 * y1;
        float cy = z0 * x1 - x0 * z1;
        float cz = x0 * y1 - y0 * x1;
        float vol = (cx * x2 + cy * y2 + cz * z2) * (1.0f / 6.0f);
        #pragma unroll
        for (int q = 0; q < NPARTS; q++) accp[q] += (p == q) ? vol : 0.f;
    }
    #pragma unroll
    for (int q = 0; q < NPARTS; q++) {
        float s = accp[q];
        #pragma unroll
        for (int off = 32; off > 0; off >>= 1) s += __shfl_down(s, off, 64);
        accp[q] = s;
    }
    if (lane == 0) {
        #pragma unroll
        for (int q = 0; q < NPARTS; q++) sredp[wave][q] = accp[q];
    }
    __syncthreads();
    if (tid < NPARTS) {
        float s = 0.f;
        #pragma unroll
        for (int w = 0; w < NWAVES; w++) s += sredp[w][tid];
        spart[tid] = s;
    }
    __syncthreads();

    // ---- Phase C: HD vertices, COM / CoP accumulators ----
    float sVx = 0.f, sVy = 0.f, sVz = 0.f, sVol = 0.f;
    float sPx = 0.f, sPy = 0.f, sPz = 0.f, sPw  = 0.f;

    #pragma unroll 2
    for (int v = tid; v < NVHD; v += NTHREADS) {
        uint4 hp = hd_pack[v];
        int i0 = hp.x & 0xFFFF, i1 = hp.x >> 16;
        int i2 = hp.y & 0xFFFF, p  = hp.y >> 16;
        float w0 = __uint_as_float(hp.z);
        float w1 = __uint_as_float(hp.w);
        float w2 = 1.0f - w0 - w1;
        float x0, y0, z0, x1, y1, z1, x2, y2, z2;
        GETV(i0, x0, y0, z0);
        GETV(i1, x1, y1, z1);
        GETV(i2, x2, y2, z2);
        float x = w0 * x0 + w1 * x1 + w2 * x2;
        float y = w0 * y0 + w1 * y1 + w2 * y2;
        float z = w0 * z0 + w1 * z1 + w2 * z2;
        float vol = spart[p];
        float pw  = (y < 0.f) ? fmaf(-100.f, y, 1.f) : __expf(-10.f * y);
        sVx += x * vol;  sVy += y * vol;  sVz += z * vol;  sVol += vol;
        sPx += x * pw;   sPy += y * pw;   sPz += z * pw;   sPw  += pw;
    }

    float vals[8] = {sVx, sVy, sVz, sVol, sPx, sPy, sPz, sPw};
    #pragma unroll
    for (int q = 0; q < 8; q++) {
        float s = vals[q];
        #pragma unroll
        for (int off = 32; off > 0; off >>= 1) s += __shfl_down(s, off, 64);
        vals[q] = s;
    }
    // reuse sredp storage (dead after spart) for the 8-value block reduction
    float* sred8 = &sredp[0][0];   // NWAVES*8*4 = 512 B <= 640 B
    if (lane == 0) {
        #pragma unroll
        for (int q = 0; q < 8; q++) sred8[wave * 8 + q] = vals[q];
    }
    __syncthreads();
    if (tid == 0) {
        float r[8];
        #pragma unroll
        for (int q = 0; q < 8; q++) {
            float s = 0.f;
            #pragma unroll
            for (int w = 0; w < NWAVES; w++) s += sred8[w * 8 + q];
            r[q] = s;
        }
        float invVol = 1.0f / r[3];
        float invPw  = 1.0f / (r[7] + 1e-6f);
        float comx = r[0] * invVol, comz = r[2] * invVol;
        float copx = r[4] * invPw,  copz = r[6] * invPw;
        float d0 = comx - copx, d2 = comz - copz;
        out[b] = sqrtf(d0 * d0 + d2 * d2);
    }
#undef GETV
}

extern "C" void kernel_launch(void* const* d_in, const int* in_sizes, int n_in,
                              void* d_out, int out_size, void* d_ws, size_t ws_size,
                              hipStream_t stream) {
    const float* vertices = (const float*)d_in[0];
    const float* bary     = (const float*)d_in[1];
    const int*   faces    = (const int*)d_in[2];
    const int*   hd_fid   = (const int*)d_in[3];
    const int*   part_fid = (const int*)d_in[4];
    float* out = (float*)d_out;

    char* ws = (char*)d_ws;
    uint2* f_pack  = (uint2*)ws;                          // NF*8 = 110208 (16B-aligned)
    uint4* hd_pack = (uint4*)(ws + (size_t)NF * 8);       // NVHD*16

    build_tables<<<(NVHD + 255) / 256, 256, 0, stream>>>(bary, faces, hd_fid, part_fid,
                                                         f_pack, hd_pack);
    stab_kernel<<<NB, NTHREADS, 0, stream>>>(vertices, f_pack, hd_pack, out);
}